// Round 10
// baseline (89.626 us; speedup 1.0000x reference)
//
#include <hip/hip_runtime.h>

// probs = |U^{x8} f|^2 / ||f||^2, U = 8x8 complex gate on each of 8 qubit triples.
// MFMA: per 3-qubit axis, D = A*B, A(16x16 f16) = [[Gr,-Gi],[Gi,Gr]], B = 16
// rest-columns of [Xr;Xi], f32 accumulate (v_mfma_f32_16x16x16_f16).
//
// k_pass1 (axes of low-15 bits; 512 blocks x 1024 thr, 128KB LDS):
//   NO LDS fill. Stage A7 reads B-fragments DIRECTLY from f (float4 of 4
//   consecutive A7; lanes kg<2, kg>=2 feed im=0; fully coalesced), ||f||^2
//   partials fused. Uniform stage-write -> L0 = [A4|A5|A6|A7|p|A3]. Then 3
//   uniform in-LDS stages (A3,A4,A5) -> L3 = [A7|A3|A4|A5|p|A6]. Final stage
//   (rows = A6) writes the intermediate in NATURAL dword order (dword index =
//   global element index; uint4 = 4 consecutive A7): per-lane accumulate
//   arr[ab][A7] across the j-loop (split by jb = A3 bit), p=0 lanes keep
//   rr in {0,1}, p=1 lanes keep rr in {2,3} (both sides of the shfl_xor have
//   the needed re/im halves), then 4 uint4 stores per jb.
//   Natural order => pass2 block read set == write set => race-free in-place.
// k_pass2 (axes A0..A2; 2048 blocks x 256 thr, 32KB LDS): round-4 VERBATIM.
//   fill 4-hi-grouped uint4 reads; 2 LDS stages; final stage A0 fused with
//   probs = (re^2+im^2)*inv. Each block reads/writes the same private
//   16-dword-per-hi slice of d_out.

typedef _Float16 f16;
typedef _Float16 f16x4 __attribute__((ext_vector_type(4)));
typedef float f32x4 __attribute__((ext_vector_type(4)));
typedef unsigned int u32;

__device__ __forceinline__ u32 SW1(u32 a) { return a ^ (((a >> 8) & 0xFu) << 3); }
__device__ __forceinline__ u32 SW2(u32 a) { return a ^ (((a >> 7) & 0x7u) << 4); }

__device__ __forceinline__ u32 PK(float x, float y) {
  return __builtin_bit_cast(u32, __builtin_amdgcn_cvt_pkrtz(x, y));
}

// A fragment for v_mfma_f32_16x16x16_f16: lane holds A[row=l&15][k=(l>>4)*4+e].
// A = [[Gr, -Gi], [Gi, Gr]]; rows 0-7 -> re out, 8-15 -> im out; k<8 hits Xr.
__device__ __forceinline__ f16x4 build_A(const float* __restrict__ gr,
                                         const float* __restrict__ gi, int l) {
  const int row = l & 15, kg = l >> 4;
  const int pg = row & 7, rpl = row >> 3, kpl = kg >> 1;
  f16x4 a;
#pragma unroll
  for (int e = 0; e < 4; ++e) {
    const int j = (kg & 1) * 4 + e;
    const float grv = gr[pg * 8 + j], giv = gi[pg * 8 + j];
    const float v = rpl == 0 ? (kpl == 0 ? grv : -giv) : (kpl == 0 ? giv : grv);
    a[e] = (f16)v;
  }
  return a;
}

__device__ __forceinline__ f32x4 MF(f16x4 A, uint2 bw, f32x4 C) {
  return __builtin_amdgcn_mfma_f32_16x16x16f16(A, __builtin_bit_cast(f16x4, bw),
                                               C, 0, 0, 0);
}

// pass1 uniform stage. GFIRST: B-frags from global f tile (k = A7, natural
// layout), norm partial fused, no mid-barrier (LDS empty). Else: in-LDS stage
// (read all -> barrier -> write all). Both end with barrier.
template <bool GFIRST>
__device__ __forceinline__ void p1_stage(char* lb, const float4* fb, f16x4 A,
                                         int w, int l, float* red) {
  const int kg = l >> 4, c = l & 15, c3 = c >> 3, p = kg >> 1;
  const u32 rb = (u32)(w * 512 + c * 32 + kg * 8);
  const f32x4 Z = {0.f, 0.f, 0.f, 0.f};
  f32x4 acc[16];
  float s = 0.f;
#pragma unroll
  for (int g = 0; g < 4; ++g) {
#pragma unroll
    for (int m = 0; m < 4; ++m) {
      const int j = (g & 1) + m * 2 + (g >> 1) * 8;
      uint2 bw = make_uint2(0u, 0u);
      if (GFIRST) {
        if (kg < 2) {
          const int A3 = j >> 1, A4 = (j & 1) * 4 + (w >> 2);
          const int A5 = (w & 3) * 2 + c3, A6 = c & 7;
          const int restn = ((A3 * 8 + A4) * 8 + A5) * 8 + A6;
          const float4 v = fb[restn * 2 + kg];
          s += v.x * v.x + v.y * v.y + v.z * v.z + v.w * v.w;
          bw = make_uint2(PK(v.x, v.y), PK(v.z, v.w));
        }
      } else {
        bw = *(const uint2*)(lb + SW1(rb + (u32)j * 8192u));
      }
      acc[g * 4 + m] = MF(A, bw, Z);
    }
  }
  if (GFIRST) {
    // fused ||f||^2 partial: reduce before the post-write barrier
#pragma unroll
    for (int off = 32; off; off >>= 1) s += __shfl_down(s, off, 64);
    if (l == 0) red[w] = s;
  } else {
    __syncthreads();  // all reads everywhere done -> in-place writes safe
  }
  const u32 wl = (u32)(((w >> 2) << 14) + (((w & 3) * 2 + c3) << 11) +
                       ((c & 7) << 8) + ((kg & 1) << 7) + (p << 4));
#pragma unroll
  for (int g = 0; g < 4; ++g) {
#pragma unroll
    for (int rr = 0; rr < 4; ++rr) {
      const u32 d0 = PK(acc[g * 4 + 0][rr], acc[g * 4 + 1][rr]);
      const u32 d1 = PK(acc[g * 4 + 2][rr], acc[g * 4 + 3][rr]);
      const u32 lg = wl + (u32)(((g & 1) << 16) + ((g >> 1) << 3) + (rr << 5));
      *(uint2*)(lb + SW1(lg)) = make_uint2(d0, d1);
    }
  }
  __syncthreads();
}

__global__ __launch_bounds__(1024, 4) void k_pass1(
    const float* __restrict__ f, const float* __restrict__ gr,
    const float* __restrict__ gi, uint4* __restrict__ st,
    float* __restrict__ wsp) {
  __shared__ __align__(16) char lb[131072];
  __shared__ float red[16];
  const int t = threadIdx.x, l = t & 63, w = t >> 6, blk = blockIdx.x;
  const int kg = l >> 4, c = l & 15, c3 = c >> 3, p = kg >> 1, kg0 = kg & 1;
  const f16x4 A = build_A(gr, gi, l);
  const f32x4 Z = {0.f, 0.f, 0.f, 0.f};
  const float4* fb = (const float4*)f + (size_t)blk * 8192;

  p1_stage<true>(lb, fb, A, w, l, red);   // A7 (from global) -> L0
  if (t == 0) {                           // red[] visible via stage barrier
    float a = 0.f;
#pragma unroll
    for (int i = 0; i < 16; ++i) a += red[i];
    wsp[blk] = a;
  }
  p1_stage<false>(lb, fb, A, w, l, red);  // A3
  p1_stage<false>(lb, fb, A, w, l, red);  // A4
  p1_stage<false>(lb, fb, A, w, l, red);  // A5

  // ---- final stage A6 + NATURAL-ORDER writeout; reads L3 = [A7|A3|A4|A5|p|A6]
  // element coords (r9-validated): A7 = j>>1, A3 = (j&1)*4 + (w>>2),
  // A4 = (w&3)*2 + c3, A5 = c&7, A6 = kg0*4 + rr. dword value = re | im<<16.
  // p=0 lane keeps rr in {0,1}; p=1 lane keeps rr in {2,3} (A6 = kg0*4+2p+ab).
  const u32 rb = (u32)(w * 512 + c * 32 + kg * 8);
  const size_t ob = (size_t)blk * 8192;  // uint4 units
  const int A4v = (w & 3) * 2 + c3, A5v = c & 15 >= 8 ? (c & 7) : (c & 7);
#pragma unroll
  for (int jb = 0; jb < 2; ++jb) {
    u32 arr[2][8];
#pragma unroll
    for (int j7 = 0; j7 < 8; ++j7) {
      const int j = j7 * 2 + jb;
      const uint2 bw = *(const uint2*)(lb + SW1(rb + (u32)j * 8192u));
      const f32x4 a = MF(A, bw, Z);
      const u32 h01 = PK(a[0], a[1]), h23 = PK(a[2], a[3]);
      const u32 q01 = __shfl_xor(h01, 32, 64), q23 = __shfl_xor(h23, 32, 64);
      // p=0: own = re halves, partner = im. p=1: own = im, partner = re.
      arr[0][j7] = p ? ((q23 & 0xffffu) | (h23 << 16))
                     : ((h01 & 0xffffu) | (q01 << 16));
      arr[1][j7] = p ? ((q23 >> 16) | (h23 & 0xffff0000u))
                     : ((h01 >> 16) | (q01 & 0xffff0000u));
    }
    const int A3v = jb * 4 + (w >> 2);
    const u32 ibase = (u32)(A3v * 1024 + A4v * 128 + A5v * 16);
#pragma unroll
    for (int ab = 0; ab < 2; ++ab) {
      const int A6v = kg0 * 4 + 2 * p + ab;
#pragma unroll
      for (int tq = 0; tq < 2; ++tq) {
        const uint4 vv = make_uint4(arr[ab][4 * tq + 0], arr[ab][4 * tq + 1],
                                    arr[ab][4 * tq + 2], arr[ab][4 * tq + 3]);
        st[ob + ibase + (u32)(A6v * 2 + tq)] = vv;  // dword = nat idx, 4x A7
      }
    }
  }
}

// ---------------- pass2: 32KB tile, 4 waves (round-4 VERBATIM) --------------
// halfword layout h = s1*2048 + s0*256 + sp*16 + p*8 + k  (byte = 2h, SW2).
// L0: k=A2,s0=A0,s1=A1 -> stage A2 -> L1: k=A1,s0=A2,s1=A0 -> stage A1 ->
// L2: k=A0,s0=A1,s1=A2 -> final stage A0 + probs.
__device__ __forceinline__ void p2_stage(char* lb, f16x4 A, int w, int l) {
  const int kg = l >> 4, c = l & 15, pp = kg >> 1;
  const f32x4 Z = {0.f, 0.f, 0.f, 0.f};
  f32x4 acc[16];
#pragma unroll
  for (int g = 0; g < 4; ++g) {
#pragma unroll
    for (int m = 0; m < 4; ++m) {
      const int j = (g & 1) + m * 2 + (g >> 1) * 8;
      const u32 rb = (u32)(j * 2048 + w * 512 + c * 32 + kg * 8);
      const uint2 bw = *(const uint2*)(lb + SW2(rb));
      acc[g * 4 + m] = MF(A, bw, Z);
    }
  }
  __syncthreads();
  // packed b128 writes: for (pe,rr), halfword slots k'=j>>1 are consecutive
#pragma unroll
  for (int pe = 0; pe < 2; ++pe) {
#pragma unroll
    for (int rr = 0; rr < 4; ++rr) {
      uint4 vv;
      vv.x = PK(acc[pe * 4 + 0][rr], acc[pe * 4 + 1][rr]);
      vv.y = PK(acc[pe * 4 + 2][rr], acc[pe * 4 + 3][rr]);
      vv.z = PK(acc[(2 + pe) * 4 + 0][rr], acc[(2 + pe) * 4 + 1][rr]);
      vv.w = PK(acc[(2 + pe) * 4 + 2][rr], acc[(2 + pe) * 4 + 3][rr]);
      const u32 wb = (u32)((pe * 4 + w) * 4096 + ((kg & 1) * 4 + rr) * 512 +
                           c * 32 + pp * 16);
      *(uint4*)(lb + SW2(wb)) = vv;
    }
  }
  __syncthreads();
}

__global__ __launch_bounds__(256, 4) void k_pass2(
    const uint4* gp, const float* __restrict__ gr, const float* __restrict__ gi,
    const float* __restrict__ wsp, float* out) {
  __shared__ __align__(16) char lb[32768];
  __shared__ float red[4];
  const int t = threadIdx.x, l = t & 63, w = t >> 6;
  const int kg = l >> 4, c = l & 15, pp = kg >> 1;
  const int b9 = blockIdx.x >> 2, q = blockIdx.x & 3;
  const f16x4 A = build_A(gr, gi, l);
  const f32x4 Z = {0.f, 0.f, 0.f, 0.f};

  // norm: reduce pass1 partials (deterministic)
  float sp_ = wsp[t] + wsp[t + 256];
#pragma unroll
  for (int off = 32; off; off >>= 1) sp_ += __shfl_down(sp_, off, 64);
  if (l == 0) red[w] = sp_;

  // ---- fill: 4-hi-grouped uint4 reads -> packed b64 plane writes ----
  // element n = hi*2^15 + b9*64 + q*16 + sp; uint4 idx = hi*8192 + b9*16 + q*4 + u
  {
    const int z = t >> 2, u = t & 3;
    const int A1 = z & 7, A0 = z >> 3;
#pragma unroll
    for (int a2g = 0; a2g < 2; ++a2g) {
      uint4 raw[4];
#pragma unroll
      for (int d = 0; d < 4; ++d)
        raw[d] = gp[(size_t)(z * 8 + 4 * a2g + d) * 8192 + (u32)(b9 * 16 + q * 4 + u)];
#pragma unroll
      for (int v = 0; v < 4; ++v) {
        const u32 w0 = v == 0 ? raw[0].x : v == 1 ? raw[0].y : v == 2 ? raw[0].z : raw[0].w;
        const u32 w1 = v == 0 ? raw[1].x : v == 1 ? raw[1].y : v == 2 ? raw[1].z : raw[1].w;
        const u32 w2 = v == 0 ? raw[2].x : v == 1 ? raw[2].y : v == 2 ? raw[2].z : raw[2].w;
        const u32 w3 = v == 0 ? raw[3].x : v == 1 ? raw[3].y : v == 2 ? raw[3].z : raw[3].w;
        const int sp = u * 4 + v;
        const u32 base = (u32)(A1 * 4096 + A0 * 512 + sp * 32 + 8 * a2g);
        // re plane (p=0): lo halves, k = A2 = 4*a2g + d consecutive
        *(uint2*)(lb + SW2(base)) =
            make_uint2((w0 & 0xffffu) | (w1 << 16), (w2 & 0xffffu) | (w3 << 16));
        // im plane (p=1)
        *(uint2*)(lb + SW2(base + 16u)) =
            make_uint2((w0 >> 16) | (w1 & 0xffff0000u), (w2 >> 16) | (w3 & 0xffff0000u));
      }
    }
  }
  __syncthreads();
  const float inv = 1.0f / (red[0] + red[1] + red[2] + red[3]);

  p2_stage(lb, A, w, l);  // A2
  p2_stage(lb, A, w, l);  // A1

  // ---- final stage A0 + probs writeout ----
  // L2: A2 = j>>1, A1 = (j&1)*4+w, sp = c; rows: p=kg>>1, A0 = (kg&1)*4+rr
#pragma unroll
  for (int j = 0; j < 16; ++j) {
    const u32 rb = (u32)(j * 2048 + w * 512 + c * 32 + kg * 8);
    const uint2 bw = *(const uint2*)(lb + SW2(rb));
    const f32x4 a = MF(A, bw, Z);
    const int A2 = j >> 1, A1 = (j & 1) * 4 + w;
    const size_t gb = ((size_t)A1 << 18) + ((size_t)A2 << 15) +
                      (u32)(b9 * 64 + q * 16 + c);
#pragma unroll
    for (int rr = 0; rr < 4; ++rr) {
      float qv = a[rr] * a[rr];
      qv += __shfl_xor(qv, 32, 64);  // re^2 + im^2 from partner plane
      if ((rr >> 1) == pp) {         // p=0 stores rr 0,1; p=1 stores rr 2,3
        const size_t A0 = (size_t)((kg & 1) * 4 + rr);
        out[gb + (A0 << 21)] = qv * inv;
      }
    }
  }
}

extern "C" void kernel_launch(void* const* d_in, const int* in_sizes, int n_in,
                              void* d_out, int out_size, void* d_ws,
                              size_t ws_size, hipStream_t stream) {
  (void)in_sizes; (void)n_in; (void)out_size; (void)ws_size;
  const float* f = (const float*)d_in[0];
  const float* gr = (const float*)d_in[1];
  const float* gi = (const float*)d_in[2];
  float* wsp = (float*)d_ws;  // 512 floats

  k_pass1<<<dim3(512), dim3(1024), 0, stream>>>(f, gr, gi, (uint4*)d_out, wsp);
  k_pass2<<<dim3(2048), dim3(256), 0, stream>>>((const uint4*)d_out, gr, gi,
                                                wsp, (float*)d_out);
}

// Round 11
// 72.636 us; speedup vs baseline: 1.2339x; 1.2339x over previous
//
#include <hip/hip_runtime.h>

// probs = |U^{x8} f|^2 / ||f||^2, U = 8x8 complex gate on each of 8 qubit triples.
// MFMA: per 3-qubit axis, D = A*B, A(16x16 f16) = [[Gr,-Gi],[Gi,Gr]], B = 16
// rest-columns of [Xr;Xi], f32 accumulate (v_mfma_f32_16x16x16_f16).
//
// 4+4 axis split (vs the serialization-bound 5+3):
//  k_pass1 (axes A4..A7, low 12 bits): 4096 blocks x 256 thr (4 waves),
//    16KB LDS -> ~6 blocks/CU (fill HBM / LDS stages / writeout of different
//    blocks overlap). Tile halfword layout [e2|e1|e0|p|k], byte =
//    e2<<11|e1<<8|e0<<5|p<<4|k<<1, swizzle SW1(a)=a^(((a>>8)&0xF)<<3).
//    fill (re plane only, +||f||^2 partials->ws) -> 3 uniform stages
//    (A4 im=0, A5, A6; rotation k<-e2, e2<-e1, e1<-e0, e0<-newdigit) ->
//    final stage A7 fused with natural-order intermediate writeout
//    (dword n = hi*4096+low12 = re|im<<16; dense 512B runs per wave).
//  k_norm: 1 block, 4096 partials -> ws[4096] = 1/sum. Deterministic.
//  k_pass2 (axes A0..A3): 1024 blocks x 512 thr (8 waves), 64KB LDS ->
//    2 blocks/CU. Block owns lows Lb*4+[0,4): reads uint4 n>>2 = hi*1024+Lb
//    (16B/lane, 64B lines shared by 4 sibling Lb -> co-XCD via chunked
//    bijective swizzle Lb=(bid%8)*128+bid/8). Tile layout [e2|e1|sp|e0|p|k],
//    byte = e2<<13|e1<<10|sp<<8|e0<<5|p<<4|k<<1, swizzle SW2 = same formula.
//    3 uniform stages (A0,A1,A2) -> final A3 fused with probs writeout
//    (re^2+im^2 via shfl_xor 32, *1/sum). Read set == write set per block
//    (same n indices) -> race-free in-place d_out.
//  All stage LDS reads/writes bank-audited: lane-varying bits XORed into the
//  bank window [6:3] by the swizzle -> wave-b64 minimum (4 dwords/bank).
//  Uses 16388 B of d_ws (4096 partials + inv).

typedef _Float16 f16;
typedef _Float16 f16x4 __attribute__((ext_vector_type(4)));
typedef float f32x4 __attribute__((ext_vector_type(4)));
typedef unsigned int u32;

__device__ __forceinline__ u32 SWZ(u32 a) { return a ^ (((a >> 8) & 0xFu) << 3); }

__device__ __forceinline__ u32 PK(float x, float y) {
  return __builtin_bit_cast(u32, __builtin_amdgcn_cvt_pkrtz(x, y));
}

// A fragment for v_mfma_f32_16x16x16_f16: lane holds A[row=l&15][k=(l>>4)*4+e].
// A = [[Gr, -Gi], [Gi, Gr]]; rows 0-7 -> re out, 8-15 -> im out; k<8 hits Xr.
__device__ __forceinline__ f16x4 build_A(const float* __restrict__ gr,
                                         const float* __restrict__ gi, int l) {
  const int row = l & 15, kg = l >> 4;
  const int pg = row & 7, rpl = row >> 3, kpl = kg >> 1;
  f16x4 a;
#pragma unroll
  for (int e = 0; e < 4; ++e) {
    const int j = (kg & 1) * 4 + e;
    const float grv = gr[pg * 8 + j], giv = gi[pg * 8 + j];
    const float v = rpl == 0 ? (kpl == 0 ? grv : -giv) : (kpl == 0 ? giv : grv);
    a[e] = (f16)v;
  }
  return a;
}

__device__ __forceinline__ f32x4 MF(f16x4 A, uint2 bw, f32x4 C) {
  return __builtin_amdgcn_mfma_f32_16x16x16f16(A, __builtin_bit_cast(f16x4, bw),
                                               C, 0, 0, 0);
}

// ---------------- pass1 ----------------
// stage: read [e2=j|e1=(w<<1)|c3|e0=c&7|p|k], write [e1old|e0old|r|p_out|j].
template <bool FIRST>
__device__ __forceinline__ void p1_stage(char* lb, f16x4 A, int w, int l) {
  const int kg = l >> 4, c = l & 15, c3 = c >> 3, kg0 = kg & 1, kg1 = kg >> 1;
  const f32x4 Z = {0.f, 0.f, 0.f, 0.f};
  const u32 rbase = (u32)((((w << 1) | c3) << 8) | ((c & 7) << 5) | (kg1 << 4) |
                          (kg0 << 3));
  f32x4 acc[8];
#pragma unroll
  for (int j = 0; j < 8; ++j) {
    uint2 bw = make_uint2(0u, 0u);
    if (!FIRST || kg < 2)
      bw = *(const uint2*)(lb + SWZ(rbase + ((u32)j << 11)));
    acc[j] = MF(A, bw, Z);
  }
  __syncthreads();  // all reads done everywhere -> in-place writes safe
  const u32 wbase = (u32)(((((w << 1) | c3)) << 11) | ((c & 7) << 8) |
                          (kg1 << 4));
#pragma unroll
  for (int q = 0; q < 2; ++q) {
#pragma unroll
    for (int rr = 0; rr < 4; ++rr) {
      const u32 d0 = PK(acc[4 * q + 0][rr], acc[4 * q + 1][rr]);
      const u32 d1 = PK(acc[4 * q + 2][rr], acc[4 * q + 3][rr]);
      const u32 lg = wbase + (u32)(((kg0 * 4 + rr) << 5) | (q << 3));
      *(uint2*)(lb + SWZ(lg)) = make_uint2(d0, d1);
    }
  }
  __syncthreads();
}

__global__ __launch_bounds__(256, 4) void k_pass1(
    const float* __restrict__ f, const float* __restrict__ gr,
    const float* __restrict__ gi, u32* __restrict__ st,
    float* __restrict__ wsp) {
  __shared__ __align__(16) char lb[16384];
  __shared__ float red[4];
  const int t = threadIdx.x, l = t & 63, w = t >> 6, b = blockIdx.x;
  const int kg = l >> 4, c = l & 15, c3 = c >> 3, kg0 = kg & 1, kg1 = kg >> 1;
  const f16x4 A = build_A(gr, gi, l);
  const f32x4 Z = {0.f, 0.f, 0.f, 0.f};

  // ---- fill L0 = [e2=A5|e1=A6|e0=A7|p|k=A4], re plane only; ||f||^2 ----
  {
    const float* fb = f + ((size_t)b << 12);
    float v[16];
#pragma unroll
    for (int u = 0; u < 2; ++u) {
      const int low9 = u * 256 + t;
#pragma unroll
      for (int a4 = 0; a4 < 8; ++a4) v[u * 8 + a4] = fb[a4 * 512 + low9];
    }
    float s = 0.f;
#pragma unroll
    for (int i = 0; i < 16; ++i) s += v[i] * v[i];
#pragma unroll
    for (int u = 0; u < 2; ++u) {
      const int low9 = u * 256 + t;
      const int A5 = low9 >> 6, A6 = (low9 >> 3) & 7, A7 = low9 & 7;
      const u32 bb = (u32)((A5 << 11) | (A6 << 8) | (A7 << 5));  // p=0, k=0
      *(uint2*)(lb + SWZ(bb)) =
          make_uint2(PK(v[u * 8 + 0], v[u * 8 + 1]), PK(v[u * 8 + 2], v[u * 8 + 3]));
      *(uint2*)(lb + SWZ(bb | 8u)) =
          make_uint2(PK(v[u * 8 + 4], v[u * 8 + 5]), PK(v[u * 8 + 6], v[u * 8 + 7]));
    }
#pragma unroll
    for (int off = 32; off; off >>= 1) s += __shfl_down(s, off, 64);
    if (l == 0) red[w] = s;
  }
  __syncthreads();
  if (t == 0) wsp[b] = (red[0] + red[1]) + (red[2] + red[3]);

  p1_stage<true>(lb, A, w, l);   // A4 (im read as 0)
  p1_stage<false>(lb, A, w, l);  // A5
  p1_stage<false>(lb, A, w, l);  // A6

  // ---- final stage A7 + natural-order intermediate writeout ----
  // reads L3 = [A4'|A5'|A6'|p|A7]; rows: p_out=kg1, A7' = kg0*4+rr.
  const u32 rbase = (u32)((((w << 1) | c3) << 8) | ((c & 7) << 5) | (kg1 << 4) |
                          (kg0 << 3));
  const u32 ob = (u32)b << 12;
#pragma unroll
  for (int j = 0; j < 8; ++j) {
    const uint2 bw = *(const uint2*)(lb + SWZ(rbase + ((u32)j << 11)));
    const f32x4 a = MF(A, bw, Z);
    const u32 h01 = PK(a[0], a[1]), h23 = PK(a[2], a[3]);
    const u32 q01 = __shfl_xor(h01, 32, 64), q23 = __shfl_xor(h23, 32, 64);
    // p0 lane stores A7' = 4kg0+{0,1} (own=re, partner=im);
    // p1 lane stores A7' = 4kg0+{2,3} (own=im, partner=re).
    const u32 d0 = kg1 ? ((q23 & 0xffffu) | (h23 << 16))
                       : ((h01 & 0xffffu) | (q01 << 16));
    const u32 d1 = kg1 ? ((q23 >> 16) | (h23 & 0xffff0000u))
                       : ((h01 >> 16) | (q01 & 0xffff0000u));
    const u32 low12 = (u32)((j << 9) | (((w << 1) | c3) << 6) | ((c & 7) << 3) |
                            (kg0 * 4 + 2 * kg1));
    *(uint2*)(st + ob + low12) = make_uint2(d0, d1);
  }
}

// ---------------- k_norm: 4096 partials -> ws[4096] = 1/sum ----------------
__global__ __launch_bounds__(256) void k_norm(float* __restrict__ wsp) {
  const int t = threadIdx.x;
  float s = 0.f;
#pragma unroll
  for (int i = 0; i < 16; ++i) s += wsp[i * 256 + t];
#pragma unroll
  for (int off = 32; off; off >>= 1) s += __shfl_down(s, off, 64);
  __shared__ float red[4];
  if ((t & 63) == 0) red[t >> 6] = s;
  __syncthreads();
  if (t == 0) wsp[4096] = 1.0f / ((red[0] + red[1]) + (red[2] + red[3]));
}

// ---------------- pass2 ----------------
// tile byte = e2<<13 | e1<<10 | sp<<8 | e0<<5 | p<<4 | k<<1.
// stage: read e2=j>>1, e1=((j&1)<<2)|(w>>1), e0=((w&1)<<2)|(c>>2), sp=c&3;
// write [e1old|e0old|sp|r|p_out|k'=e2old], packing j-groups {j0,j0+2,j0+4,j0+6}.
__device__ __forceinline__ void p2_stage(char* lb, f16x4 A, int w, int l) {
  const int kg = l >> 4, c = l & 15, kg0 = kg & 1, kg1 = kg >> 1;
  const int spc = c & 3, c2b = c >> 2;
  const f32x4 Z = {0.f, 0.f, 0.f, 0.f};
  f32x4 acc[16];
#pragma unroll
  for (int j = 0; j < 16; ++j) {
    const u32 rb = (u32)(((j >> 1) << 13) | (((((j & 1) << 2) | (w >> 1))) << 10) |
                         (spc << 8) | (((((w & 1) << 2) | c2b)) << 5) |
                         (kg1 << 4) | (kg0 << 3));
    acc[j] = MF(A, *(const uint2*)(lb + SWZ(rb)), Z);
  }
  __syncthreads();
  const u32 wb0 = (u32)((((((w & 1) << 2) | c2b)) << 10) | (spc << 8) | (kg1 << 4));
#pragma unroll
  for (int jp = 0; jp < 4; ++jp) {
    const int j0 = (jp & 1) | ((jp >> 1) << 3);  // {0,1,8,9}
#pragma unroll
    for (int rr = 0; rr < 4; ++rr) {
      const u32 d0 = PK(acc[j0][rr], acc[j0 + 2][rr]);
      const u32 d1 = PK(acc[j0 + 4][rr], acc[j0 + 6][rr]);
      const u32 lg = wb0 + (u32)(((((j0 & 1) << 2) | (w >> 1)) << 13) |
                                 ((kg0 * 4 + rr) << 5) | ((j0 >> 3) << 3));
      *(uint2*)(lb + SWZ(lg)) = make_uint2(d0, d1);
    }
  }
  __syncthreads();
}

__global__ __launch_bounds__(512, 4) void k_pass2(
    const uint4* __restrict__ gp, const float* __restrict__ gr,
    const float* __restrict__ gi, const float* __restrict__ invp,
    float* __restrict__ out) {
  __shared__ __align__(16) char lb[65536];
  const int t = threadIdx.x, l = t & 63, w = t >> 6;
  const int kg = l >> 4, c = l & 15, kg0 = kg & 1, kg1 = kg >> 1;
  const int spc = c & 3, c2b = c >> 2;
  const int bid = blockIdx.x;
  const int Lb = (bid & 7) * 128 + (bid >> 3);  // bijective; Lb-neighbors co-XCD
  const f16x4 A = build_A(gr, gi, l);
  const f32x4 Z = {0.f, 0.f, 0.f, 0.f};

  // ---- fill L0 = [e2=A1|e1=A2|sp|e0=A3|p|k=A0] ----
  // t = A1<<6 | A2<<3 | A3; loads uint4 (4 sp) per A0 at idx (A0*512+t)*1024+Lb.
  {
    uint4 r8[8];
#pragma unroll
    for (int a0 = 0; a0 < 8; ++a0)
      r8[a0] = gp[(size_t)(a0 * 512 + t) * 1024 + (u32)Lb];
    const int A1 = t >> 6, A2 = (t >> 3) & 7, A3 = t & 7;
    const u32 fb = (u32)((A1 << 13) | (A2 << 10) | (A3 << 5));
#pragma unroll
    for (int sp = 0; sp < 4; ++sp) {
      u32 dv[8];
#pragma unroll
      for (int a0 = 0; a0 < 8; ++a0) {
        const uint4 r = r8[a0];
        dv[a0] = sp == 0 ? r.x : sp == 1 ? r.y : sp == 2 ? r.z : r.w;
      }
      const u32 bb = fb + (u32)(sp << 8);
      // re plane (p=0): halves k=A0 0..7
      *(uint2*)(lb + SWZ(bb)) =
          make_uint2((dv[0] & 0xffffu) | (dv[1] << 16), (dv[2] & 0xffffu) | (dv[3] << 16));
      *(uint2*)(lb + SWZ(bb | 8u)) =
          make_uint2((dv[4] & 0xffffu) | (dv[5] << 16), (dv[6] & 0xffffu) | (dv[7] << 16));
      // im plane (p=1)
      *(uint2*)(lb + SWZ(bb | 16u)) =
          make_uint2((dv[0] >> 16) | (dv[1] & 0xffff0000u), (dv[2] >> 16) | (dv[3] & 0xffff0000u));
      *(uint2*)(lb + SWZ(bb | 24u)) =
          make_uint2((dv[4] >> 16) | (dv[5] & 0xffff0000u), (dv[6] >> 16) | (dv[7] & 0xffff0000u));
    }
  }
  __syncthreads();
  const float inv = invp[0];

  p2_stage(lb, A, w, l);  // A0
  p2_stage(lb, A, w, l);  // A1
  p2_stage(lb, A, w, l);  // A2

  // ---- final stage A3 + probs writeout ----
  // reads L3 = [A0'|A1'|sp|A2'|p|A3]; rows: p_out=kg1, A3' = kg0*4+rr.
#pragma unroll
  for (int j = 0; j < 16; ++j) {
    const u32 rb = (u32)(((j >> 1) << 13) | (((((j & 1) << 2) | (w >> 1))) << 10) |
                         (spc << 8) | (((((w & 1) << 2) | c2b)) << 5) |
                         (kg1 << 4) | (kg0 << 3));
    const f32x4 a = MF(A, *(const uint2*)(lb + SWZ(rb)), Z);
    float qv0 = a[0] * a[0]; qv0 += __shfl_xor(qv0, 32, 64);
    float qv1 = a[1] * a[1]; qv1 += __shfl_xor(qv1, 32, 64);
    float qv2 = a[2] * a[2]; qv2 += __shfl_xor(qv2, 32, 64);
    float qv3 = a[3] * a[3]; qv3 += __shfl_xor(qv3, 32, 64);
    const u32 hib = (u32)(((j >> 1) << 9) | ((((j & 1) << 2) | (w >> 1)) << 6) |
                          ((((w & 1) << 2) | c2b) << 3));
    // p0 lane stores A3' = 4kg0+{0,1}; p1 lane stores A3' = 4kg0+{2,3}
    const u32 a3b = (u32)(kg0 * 4 + 2 * kg1);
    const size_t n0 = ((size_t)(hib + a3b) << 12) + (u32)(Lb * 4 + spc);
    out[n0] = (kg1 ? qv2 : qv0) * inv;
    out[n0 + 4096] = (kg1 ? qv3 : qv1) * inv;
  }
}

extern "C" void kernel_launch(void* const* d_in, const int* in_sizes, int n_in,
                              void* d_out, int out_size, void* d_ws,
                              size_t ws_size, hipStream_t stream) {
  (void)in_sizes; (void)n_in; (void)out_size; (void)ws_size;
  const float* f = (const float*)d_in[0];
  const float* gr = (const float*)d_in[1];
  const float* gi = (const float*)d_in[2];
  float* wsp = (float*)d_ws;  // 4096 partials + wsp[4096] = 1/sum (16388 B)

  k_pass1<<<dim3(4096), dim3(256), 0, stream>>>(f, gr, gi, (u32*)d_out, wsp);
  k_norm<<<dim3(1), dim3(256), 0, stream>>>(wsp);
  k_pass2<<<dim3(1024), dim3(512), 0, stream>>>((const uint4*)d_out, gr, gi,
                                                wsp + 4096, (float*)d_out);
}